// Round 1
// 1815.551 us; speedup vs baseline: 1.9228x; 1.9228x over previous
//
#include <hip/hip_runtime.h>

// Round 14: wavefront-pipeline the 4 LSTM2 layers across blocks.
//  - k_scan2p: ALL of LSTM2 in one kernel. 32 blocks = 4 layers x 8 sample-
//    groups (4 samples each). Layer l trails layer l-1 by ~2-4 steps; h(t)
//    handoff via device-coherent (sc0 sc1) stores + per-wave monotonic flags.
//    Wih GEMM fused into the scan (k_xg removed; 134MB of xg traffic gone).
//    Sequential depth: 4096 steps -> ~1024 + pipeline fill.
//  - Hot loop VMEM is all inline asm; ONE vmcnt(0)/step draining only
//    1-step-old ops (x(t+2) prefetch, h(t) publish, flag prefetch) so no
//    memory latency sits on the serial recurrence chain.
//  - k_scan1all / bn2 / head / preps unchanged from R13 (prepw2 also zeroes
//    flags each launch so graph replays are safe).

typedef _Float16 f16x8  __attribute__((ext_vector_type(8)));
typedef float    f32x4  __attribute__((ext_vector_type(4)));

#define DEVI static __device__ __forceinline__

constexpr int   T1c   = 20;
constexpr int   EMBc  = 32;
constexpr int   H1c   = 64;
constexpr int   LMAXc = 1024;
constexpr int   VOCABc= 85;
constexpr int   Ntot  = 24832;           // sum of lengths
constexpr int   NTc   = Ntot * T1c;      // 496640
constexpr int   R2c   = 32 * LMAXc;      // 32768
constexpr float EPSc  = 1e-5f;

DEVI float sigm(float x)   { return 1.f / (1.f + __expf(-x)); }
DEVI float tanhf_(float x) { return 1.f - 2.f / (1.f + __expf(2.f * x)); }

DEVI void barrier_lds() {                // barrier draining LDS only (not vmcnt)
    asm volatile("s_waitcnt lgkmcnt(0)\n\ts_barrier" ::: "memory");
}
DEVI void drain_vmem() {
    asm volatile("s_waitcnt vmcnt(0)" ::: "memory");
}

// ---------------- prep: LSTM1 combined fp16 [4][256][128] = [Wih|pad|Whh]
__global__ void __launch_bounds__(256)
k_prepw1(const float* __restrict__ Wih0, const float* __restrict__ Whh0,
         const float* __restrict__ WihS, const float* __restrict__ WhhS,
         _Float16* __restrict__ out)
{
    int i = blockIdx.x * 256 + threadIdx.x;
    if (i >= 4 * 256 * 128) return;
    int l = i >> 15, rem = i & 32767, r = rem >> 7, k = rem & 127;
    float v;
    if (l == 0) {
        if (k < 32)      v = Wih0[r * 32 + k];
        else if (k < 64) v = 0.f;
        else             v = Whh0[r * 64 + (k - 64)];
    } else {
        if (k < 64)      v = WihS[((l - 1) * 256 + r) * 64 + k];
        else             v = WhhS[((l - 1) * 256 + r) * 64 + (k - 64)];
    }
    out[i] = (_Float16)v;
}

// ---------------- prep: LSTM2 wih16 [4][512][128] (l0 zero-padded) + whh16
// also zeroes the pipeline flags for this launch (stream-ordered before scan)
__global__ void __launch_bounds__(256)
k_prepw2(const float* __restrict__ Wih0, const float* __restrict__ WihS,
         const float* __restrict__ Whh0, const float* __restrict__ WhhS,
         _Float16* __restrict__ wih, _Float16* __restrict__ whh,
         int* __restrict__ flags)
{
    int i = blockIdx.x * 256 + threadIdx.x;
    if (i < 256) flags[i] = 0;
    if (i >= 2 * 4 * 512 * 128) return;
    int half = i >> 18, rem = i & 262143;
    int l = rem >> 16, r = (rem >> 7) & 511, k = rem & 127;
    if (half == 0) {
        float v = (l == 0) ? ((k < 64) ? Wih0[r * 64 + k] : 0.f)
                           : WihS[((l - 1) * 512 + r) * 128 + k];
        wih[rem] = (_Float16)v;
    } else {
        float v = (l == 0) ? Whh0[r * 128 + k]
                           : WhhS[((l - 1) * 512 + r) * 128 + k];
        whh[rem] = (_Float16)v;
    }
}

// ---------------- LSTM1: embed + 4 layers fused, one kernel. 32 samples/WG,
// 256 thr = 4 waves. Uniform K=128 body ([x(64, l0 zero-padded)|h(64)]).
__global__ void __launch_bounds__(256)
k_scan1all(const int* __restrict__ atoms, const float* __restrict__ ew,
           const _Float16* __restrict__ W16all,
           const float* __restrict__ b0, const float* __restrict__ bS,
           _Float16* __restrict__ seq, float* __restrict__ dacc)
{
    constexpr int SX = 136;
    __shared__ alignas(16) _Float16 xh[32 * SX];     // 8.7 KB
    __shared__ float ewl[VOCABc * EMBc];             // 10.9 KB
    __shared__ int   aidl[32 * T1c];                 // 2.5 KB

    const int tid  = threadIdx.x;
    const int lane = tid & 63;
    const int wv   = tid >> 6;
    const int l16  = lane & 15;
    const int quad = lane >> 4;
    const int n0   = blockIdx.x * 32;
    const int d    = wv * 16 + l16;

    for (int i = tid; i < VOCABc * EMBc; i += 256) ewl[i] = ew[i];
    for (int i = tid; i < 32 * T1c; i += 256) aidl[i] = atoms[n0 * T1c + i];

    float daccv[2][4];
#pragma unroll
    for (int mt = 0; mt < 2; ++mt)
#pragma unroll
        for (int r = 0; r < 4; ++r) daccv[mt][r] = 0.f;

    __syncthreads();

#pragma unroll 1
    for (int l = 0; l < 4; ++l) {
        const _Float16* W16  = W16all + (size_t)l * 256 * 128;
        const float*    bptr = (l == 0) ? b0 : bS + (l - 1) * 256;

        float bias[4];
#pragma unroll
        for (int g = 0; g < 4; ++g) bias[g] = bptr[g * 64 + d];

        f16x8 wF[4][4];
#pragma unroll
        for (int kc = 0; kc < 4; ++kc) {
            const int kb = kc * 32 + quad * 8;
#pragma unroll
            for (int g = 0; g < 4; ++g)
                wF[kc][g] = *(const f16x8*)&W16[(size_t)(g * 64 + d) * 128 + kb];
        }

        f32x4 c[2];
        c[0] = {1.f, 1.f, 1.f, 1.f};
        c[1] = {1.f, 1.f, 1.f, 1.f};

        drain_vmem();            // prev layer's seq stores complete (same CU)
        __syncthreads();

        // h(t=-1) = 1; layer 0: zero x cols [32,64) once (zero weights there)
#pragma unroll
        for (int mt = 0; mt < 2; ++mt)
#pragma unroll
            for (int r = 0; r < 4; ++r)
                xh[(mt * 16 + quad * 4 + r) * SX + 64 + d] = (_Float16)1.0f;
        if (l == 0)
            for (int idx = tid; idx < 32 * 32; idx += 256) {
                int s = idx >> 5, e = idx & 31;
                xh[s * SX + 32 + e] = (_Float16)0.f;
            }

#pragma unroll 1
        for (int t = 0; t < T1c; ++t) {
            if (l == 0) {
                for (int idx = tid; idx < 32 * 32; idx += 256) {
                    int s = idx >> 5, e = idx & 31;
                    int id = aidl[s * T1c + t];
                    xh[s * SX + e] = (_Float16)(ewl[id * EMBc + e] * (float)id);
                }
            } else {
                for (int idx = tid; idx < 32 * 8; idx += 256) {
                    int s = idx >> 3, k8 = idx & 7;
                    *(f16x8*)&xh[s * SX + k8 * 8] =
                        *(const f16x8*)&seq[((size_t)(n0 + s) * T1c + t) * H1c + k8 * 8];
                }
            }
            __syncthreads();

            f32x4 acc[2][4];
#pragma unroll
            for (int mt = 0; mt < 2; ++mt)
#pragma unroll
                for (int g = 0; g < 4; ++g)
                    acc[mt][g] = {bias[g], bias[g], bias[g], bias[g]};

#pragma unroll
            for (int kc = 0; kc < 4; ++kc) {
                const int kb = kc * 32 + quad * 8;
                f16x8 ah[2];
#pragma unroll
                for (int mt = 0; mt < 2; ++mt)
                    ah[mt] = *(const f16x8*)&xh[(mt * 16 + l16) * SX + kb];
#pragma unroll
                for (int g = 0; g < 4; ++g)
#pragma unroll
                    for (int mt = 0; mt < 2; ++mt)
                        acc[mt][g] = __builtin_amdgcn_mfma_f32_16x16x32_f16(ah[mt], wF[kc][g], acc[mt][g], 0, 0, 0);
            }
            __syncthreads();

#pragma unroll
            for (int mt = 0; mt < 2; ++mt)
#pragma unroll
                for (int r = 0; r < 4; ++r) {
                    float iv = sigm(acc[mt][0][r]);
                    float fv = sigm(acc[mt][1][r]);
                    float gv = tanhf_(acc[mt][2][r]);
                    float ov = sigm(acc[mt][3][r]);
                    float cv = fv * c[mt][r] + iv * gv;
                    c[mt][r] = cv;
                    float hv = ov * tanhf_(cv);
                    _Float16 hf = (_Float16)hv;
                    int s = mt * 16 + quad * 4 + r;
                    xh[s * SX + 64 + d] = hf;
                    if (l < 3)
                        seq[((size_t)(n0 + s) * T1c + t) * H1c + d] = hf;
                    if (t == T1c - 1)
                        daccv[mt][r] += 0.25f * (hv + cv);
                }
        }
    }
#pragma unroll
    for (int mt = 0; mt < 2; ++mt)
#pragma unroll
        for (int r = 0; r < 4; ++r) {
            int s = mt * 16 + quad * 4 + r;
            dacc[(size_t)(n0 + s) * H1c + d] = daccv[mt][r];
        }
}

// ---------------- BN2 stats
__global__ void __launch_bounds__(256)
k_bn2_stats(const int* __restrict__ lens, const float* __restrict__ dacc,
            float* __restrict__ stats)
{
    int b = blockIdx.x;
    int off = 0;
    for (int i = 0; i < b; ++i) off += lens[i];
    int len = lens[b];
    const float* base = dacc + (long)off * H1c;
    float s = 0.f, ss = 0.f;
    int total = len * H1c;
    for (int i = threadIdx.x; i < total; i += 256) { float v = base[i]; s += v; ss += v * v; }
    __shared__ float rs[256], rss[256];
    rs[threadIdx.x] = s; rss[threadIdx.x] = ss;
    __syncthreads();
    for (int st = 128; st > 0; st >>= 1) {
        if (threadIdx.x < st) { rs[threadIdx.x] += rs[threadIdx.x + st]; rss[threadIdx.x] += rss[threadIdx.x + st]; }
        __syncthreads();
    }
    if (threadIdx.x == 0) {
        float m = rs[0] / (float)(LMAXc * H1c);
        float v = rss[0] / (float)(LMAXc * H1c) - m * m;
        stats[b]      = m;
        stats[32 + b] = rsqrtf(fmaxf(v, 0.f) + EPSc);
        stats[64 + b] = (float)off;
    }
}

// ---------------- BN2 apply -> LSTM2 layer-0 input, fp16, rows (t*32+b) of 128
__global__ void __launch_bounds__(256)
k_bn2_apply(const float* __restrict__ dacc, const float* __restrict__ stats,
            const int* __restrict__ lens, const float* __restrict__ g,
            const float* __restrict__ bb, _Float16* __restrict__ outA)
{
    int i = blockIdx.x * 256 + threadIdx.x;
    if (i >= R2c * 128) return;
    int rr = i >> 7, k = i & 127;
    int b = rr >> 10, p = rr & 1023;
    float y = 0.f;
    if (k < H1c) {
        int off = (int)stats[64 + b];
        float x = (p < lens[b]) ? dacc[(off + p) * H1c + k] : 0.f;
        y = (x - stats[b]) * stats[32 + b] * g[b] + bb[b];
    }
    outA[(size_t)(p * 32 + b) * 128 + k] = (_Float16)y;
}

DEVI float qsel(f32x4 a, int quad) {     // a[quad] via cndmask
    float t01 = (quad & 1) ? a[1] : a[0];
    float t23 = (quad & 1) ? a[3] : a[2];
    return (quad & 2) ? t23 : t01;
}

// fresh spin on 8 per-wave producer flags (lanes 0..7 each watch one flag)
DEVI void spin_ge(const int* fl, int lane, int need)
{
    for (;;) {
        int f = 0x7fffffff;
        if (lane < 8)
            asm volatile("global_load_dword %0, %1, off sc0 sc1\n\ts_waitcnt vmcnt(0)"
                         : "+v"(f) : "v"(fl) : "memory");
        if (__all(f >= need)) break;
    }
}

// ---------------- LSTM2: all 4 layers, wavefront-pipelined across blocks.
// 32 blocks = (layer l = bx&3) x (sample group g = bx>>2, 4 samples each).
// Per block: 512 thr = 8 waves, wave w owns cells w*16..w*16+15, lane quad =
// sample. Per step: acc = bias + Wih*x(t) + Whh*h(t-1)  (32 MFMAs/wave).
// x(t): l==0 from seqA (plain loads); l>0 from hbuf[l-1][g] (sc0 sc1 loads),
// gated by per-wave monotonic flags (flag=t <=> h(0..t-1) visible at agent
// scope). Producer never waits; 32 blocks are all co-resident (<=1/CU).
// All hot-loop VMEM is inline asm; the single vmcnt(0) per step (ph3) only
// drains ops issued in the PREVIOUS step, so nothing memory-latency-bound
// sits on the serial recurrence chain.
__global__ void __launch_bounds__(512, 2)
k_scan2p(const _Float16* __restrict__ seqA,   // [32768][128] l0 input
         const _Float16* __restrict__ wihAll, // [4][512][128] fp16
         const _Float16* __restrict__ whhAll, // [4][512][128] fp16
         const float* __restrict__ b0,        // [512]
         const float* __restrict__ bS,        // [3][512]
         _Float16* __restrict__ hbuf,         // [3][8][1024*512] fp16
         int* __restrict__ flags,             // [3][8][8]
         float* __restrict__ c2)              // [4][32][128]
{
    constexpr int SH = 144;
    __shared__ alignas(16) _Float16 av[2][4 * SH];   // h(t-1) double buffer
    __shared__ alignas(16) _Float16 xp[2][4 * SH];   // x(t) double buffer

    const int bx   = blockIdx.x;
    const int l    = bx & 3;
    const int g    = bx >> 2;
    const int tid  = threadIdx.x;
    const int lane = tid & 63;
    const int w    = tid >> 6;
    const int l16  = lane & 15;
    const int quad = lane >> 4;
    const int cell = w * 16 + l16;

    const _Float16* Wih = wihAll + (size_t)l * 512 * 128;
    const _Float16* Whh = whhAll + (size_t)l * 512 * 128;
    const float*   bptr = (l == 0) ? b0 : bS + (l - 1) * 512;

    // weights + bias resident in registers (~128 VGPR)
    f16x8 wI[4][4], wH[4][4];
    float bia[4];
#pragma unroll
    for (int g4 = 0; g4 < 4; ++g4) {
        bia[g4] = bptr[g4 * 128 + cell];
#pragma unroll
        for (int kc = 0; kc < 4; ++kc) {
            wI[g4][kc] = *(const f16x8*)&Wih[(size_t)(g4 * 128 + cell) * 128 + kc * 32 + quad * 8];
            wH[g4][kc] = *(const f16x8*)&Whh[(size_t)(g4 * 128 + cell) * 128 + kc * 32 + quad * 8];
        }
    }

    // consumer-side x tile: 1KB/step = 256 dwords; all 512 threads load
    // (tid>=256 duplicate) so vmcnt accounting is wave-uniform.
    const int ci   = tid & 255;
    const int csam = ci >> 6;         // sample 0..3
    const int coff = ci & 63;         // dword within 128-fp16 row

    const int lm = (l > 0) ? (l - 1) : 0;
    const int lp = (l < 3) ? l : 0;

    const unsigned* xdw;
    int xstep;                        // dwords per t
    if (l == 0) {
        xdw   = (const unsigned*)seqA + ((size_t)(g * 4 + csam)) * 64 + coff;
        xstep = 32 * 64;
    } else {
        xdw   = (const unsigned*)(hbuf + ((size_t)(lm * 8 + g)) * (LMAXc * 512)) + ci;
        xstep = 256;
    }

    _Float16*  hp     = hbuf + ((size_t)(lp * 8 + g)) * (LMAXc * 512) + quad * 128 + cell;
    int*       myflag = flags + (lp * 8 + g) * 8 + w;
    const int* sflag  = flags + (lm * 8 + g) * 8 + (lane & 7);

    // init h(-1) = 1, c(-1) = 1
    { int s = tid >> 7, e = tid & 127; av[0][s * SH + e] = (_Float16)1.0f; }
    float cst = 1.f;

    // prologue: x(0) -> xp[0]; x(1) load left in flight (drained at t=0 ph3)
    unsigned rL;
    if (l > 0) spin_ge(sflag, lane, 1);
    {
        unsigned r0;
        if (l == 0)
            asm volatile("global_load_dword %0, %1, off" : "=v"(r0) : "v"(xdw) : "memory");
        else
            asm volatile("global_load_dword %0, %1, off sc0 sc1" : "=v"(r0) : "v"(xdw) : "memory");
        asm volatile("s_waitcnt vmcnt(0)" ::: "memory");
        *(unsigned*)&xp[0][csam * SH + 2 * coff] = r0;
    }
    if (l > 0) spin_ge(sflag, lane, 2);
    {
        const unsigned* p1 = xdw + xstep;
        if (l == 0)
            asm volatile("global_load_dword %0, %1, off" : "=v"(rL) : "v"(p1) : "memory");
        else
            asm volatile("global_load_dword %0, %1, off sc0 sc1" : "=v"(rL) : "v"(p1) : "memory");
    }
    const unsigned* xq = xdw + 2 * (size_t)xstep;   // -> x(t+2) at loop step t
    int fpre = 0;                                   // prefetched flag value
    __syncthreads();

    int p = 0;
#pragma unroll 1
    for (int t = 0; t < LMAXc; ++t) {
        const _Float16* avR = av[p];
        _Float16*       avW = av[p ^ 1];
        const _Float16* xpR = xp[t & 1];
        _Float16*       xpW = xp[(t + 1) & 1];

        // ph1: LDS -> A fragments (rows 0..3 = samples, bcast per quad group)
        f16x8 ah[4], ax[4];
#pragma unroll
        for (int kc = 0; kc < 4; ++kc) {
            ah[kc] = *(const f16x8*)&avR[(l16 & 3) * SH + kc * 32 + quad * 8];
            ax[kc] = *(const f16x8*)&xpR[(l16 & 3) * SH + kc * 32 + quad * 8];
        }

        // ph2: acc = bias + Wih*x(t) + Whh*h(t-1)
        f32x4 acc[4];
#pragma unroll
        for (int g4 = 0; g4 < 4; ++g4) acc[g4] = {bia[g4], bia[g4], bia[g4], bia[g4]};
#pragma unroll
        for (int kc = 0; kc < 4; ++kc)
#pragma unroll
            for (int g4 = 0; g4 < 4; ++g4)
                acc[g4] = __builtin_amdgcn_mfma_f32_16x16x32_f16(ax[kc], wI[g4][kc], acc[g4], 0, 0, 0);
#pragma unroll
        for (int kc = 0; kc < 4; ++kc)
#pragma unroll
            for (int g4 = 0; g4 < 4; ++g4)
                acc[g4] = __builtin_amdgcn_mfma_f32_16x16x32_f16(ah[kc], wH[g4][kc], acc[g4], 0, 0, 0);

        // ph3: drain 1-step-old VMEM (x(t+1) load, h(t-1) store, flag pf),
        // publish flag=t (h(0..t-1) now agent-visible), stash x(t+1) in LDS.
        asm volatile("s_waitcnt vmcnt(0)" ::: "memory");
        __builtin_amdgcn_sched_barrier(0);
        if (l < 3) {
            if (lane == 0)
                asm volatile("global_store_dword %0, %1, off sc0 sc1"
                             :: "v"(myflag), "v"(t) : "memory");
        }
        if (t < LMAXc - 1)
            *(unsigned*)&xpW[csam * SH + 2 * coff] = rL;

        // ph4: gate math (serial chain)
        float gi = qsel(acc[0], quad);
        float gf = qsel(acc[1], quad);
        float gg = qsel(acc[2], quad);
        float go = qsel(acc[3], quad);
        float cv = sigm(gf) * cst + sigm(gi) * tanhf_(gg);
        cst = cv;
        float hv = sigm(go) * tanhf_(cv);
        _Float16 hf = (_Float16)hv;
        avW[quad * SH + cell] = hf;

        // ph6: upstream readiness for x(t+2) (register check; spin = startup only)
        if (l > 0 && t <= LMAXc - 3) {
            int need = t + 3;
            if (!__all((lane >= 8) || (fpre >= need))) spin_ge(sflag, lane, need);
        }
        // ph6b: issue x(t+2) load (drained next step ph3)
        if (t <= LMAXc - 3) {
            if (l == 0)
                asm volatile("global_load_dword %0, %1, off" : "=v"(rL) : "v"(xq) : "memory");
            else
                asm volatile("global_load_dword %0, %1, off sc0 sc1" : "=v"(rL) : "v"(xq) : "memory");
        }
        xq += xstep;
        // ph6c: publish h(t) (drained next step ph3, before flag=t+1)
        if (l < 3) {
            unsigned hb = (unsigned)__builtin_bit_cast(unsigned short, hf);
            asm volatile("global_store_short %0, %1, off sc0 sc1"
                         :: "v"(hp), "v"(hb) : "memory");
        }
        hp += 512;
        // ph6d: flag prefetch for next step's check
        if (l > 0) {
            if (lane < 8)
                asm volatile("global_load_dword %0, %1, off sc0 sc1"
                             : "+v"(fpre) : "v"(sflag) : "memory");
        }

        barrier_lds();
        p ^= 1;
    }

    // epilogue: final publish (h(1023) drained), flag=1024
    asm volatile("s_waitcnt vmcnt(0)" ::: "memory");
    if (l < 3 && lane == 0) {
        int fin = LMAXc;
        asm volatile("global_store_dword %0, %1, off sc0 sc1"
                     :: "v"(myflag), "v"(fin) : "memory");
    }
    c2[(size_t)l * 4096 + (g * 4 + quad) * 128 + cell] = 0.25f * cst;
}

// ---------------- head: BN3 + MLP + relu(sum), single WG fp32
DEVI void bn_rows_dev(float* X, int K, const float* g, const float* bb,
                      float* mv, int tid)
{
    __syncthreads();
    if (tid < 32) {
        float s = 0.f, ss = 0.f;
        const float* r = X + tid * K;
        for (int k = 0; k < K; ++k) { float v = r[k]; s += v; ss += v * v; }
        float m = s / (float)K;
        float vv = ss / (float)K - m * m;
        mv[tid]      = m;
        mv[32 + tid] = rsqrtf(fmaxf(vv, 0.f) + EPSc);
    }
    __syncthreads();
    for (int i = tid; i < 32 * K; i += 256) {
        int b = i / K;
        X[i] = (X[i] - mv[b]) * mv[32 + b] * g[b] + bb[b];
    }
    __syncthreads();
}

DEVI void lin_dev(const float* X, int K, const float* W, const float* bias,
                  int NO, float* Y, int relu, int tid)
{
    __syncthreads();
    for (int i = tid; i < 32 * NO; i += 256) {
        int b = i / NO, j = i - b * NO;
        float a = bias[j];
        const float* xr = X + b * K;
        const float* wr = W + j * K;
        for (int k = 0; k < K; ++k) a += xr[k] * wr[k];
        Y[i] = relu ? fmaxf(a, 0.f) : a;
    }
    __syncthreads();
}

__global__ void __launch_bounds__(256)
k_head(const float* __restrict__ c2, const float* __restrict__ g3, const float* __restrict__ bb3,
       const float* w1, const float* b1, const float* w2, const float* b2,
       const float* w22, const float* b22, const float* w3, const float* b3,
       const float* w4, const float* b4, const float* w5, const float* b5,
       float* __restrict__ out)
{
    __shared__ float A[32 * 128];
    __shared__ float Bf[32 * 128];
    __shared__ float mv[64];
    const int tid = threadIdx.x;

    for (int i = tid; i < 32 * 128; i += 256)
        A[i] = c2[i] + c2[4096 + i] + c2[8192 + i] + c2[12288 + i];
    bn_rows_dev(A, 128, g3, bb3, mv, tid);
    lin_dev(A, 128, w1, b1, 128, Bf, 1, tid);
    lin_dev(Bf, 128, w2, b2, 64, A, 1, tid);
    bn_rows_dev(A, 64, g3, bb3, mv, tid);
    lin_dev(A, 64, w22, b22, 64, Bf, 1, tid);
    lin_dev(Bf, 64, w3, b3, 32, A, 1, tid);
    lin_dev(A, 32, w4, b4, 32, Bf, 1, tid);
    lin_dev(Bf, 32, w5, b5, 16, A, 0, tid);
    if (tid < 32) {
        float s = 0.f;
        for (int j = 0; j < 16; ++j) s += A[tid * 16 + j];
        out[tid] = fmaxf(s, 0.f);
    }
}

// ---------------- host
extern "C" void kernel_launch(void* const* d_in, const int* in_sizes, int n_in,
                              void* d_out, int out_size, void* d_ws, size_t ws_size,
                              hipStream_t stream)
{
    const int*   atoms  = (const int*)d_in[0];
    const int*   lens   = (const int*)d_in[2];
    const float* embw   = (const float*)d_in[5];
    const float* l1Wih0 = (const float*)d_in[6];
    const float* l1Whh0 = (const float*)d_in[7];
    const float* l1b0   = (const float*)d_in[8];
    const float* l1Wih  = (const float*)d_in[9];
    const float* l1Whh  = (const float*)d_in[10];
    const float* l1b    = (const float*)d_in[11];
    const float* l2Wih0 = (const float*)d_in[12];
    const float* l2Whh0 = (const float*)d_in[13];
    const float* l2b0   = (const float*)d_in[14];
    const float* l2Wih  = (const float*)d_in[15];
    const float* l2Whh  = (const float*)d_in[16];
    const float* l2b    = (const float*)d_in[17];
    const float* bn2g   = (const float*)d_in[18];
    const float* bn2b   = (const float*)d_in[19];
    const float* bn3g   = (const float*)d_in[20];
    const float* bn3b   = (const float*)d_in[21];
    const float* w1  = (const float*)d_in[22]; const float* b1  = (const float*)d_in[23];
    const float* w2  = (const float*)d_in[24]; const float* b2  = (const float*)d_in[25];
    const float* w22 = (const float*)d_in[26]; const float* b22 = (const float*)d_in[27];
    const float* w3  = (const float*)d_in[28]; const float* b3  = (const float*)d_in[29];
    const float* w4  = (const float*)d_in[30]; const float* b4  = (const float*)d_in[31];
    const float* w5  = (const float*)d_in[32]; const float* b5  = (const float*)d_in[33];
    float* out = (float*)d_out;

    char* base = (char*)d_ws;
    size_t off = 0;
    auto take = [&](size_t bytes) -> char* {
        char* p = base + off;
        off = (off + bytes + 255) & ~(size_t)255;
        return p;
    };
    _Float16* seq1f  = (_Float16*)take((size_t)NTc * H1c * 2);               // 63.6 MB
    float*    dacc   = (float*)take((size_t)Ntot * H1c * 4);                 // 6.4 MB
    _Float16* wcomb1 = (_Float16*)take((size_t)4 * 256 * 128 * 2);           // 256 KB
    _Float16* wih16  = (_Float16*)take((size_t)4 * 512 * 128 * 2);           // 512 KB
    _Float16* whh16  = (_Float16*)take((size_t)4 * 512 * 128 * 2);           // 512 KB
    _Float16* seqA   = (_Float16*)take((size_t)R2c * 128 * 2);               // 8.4 MB
    _Float16* hbuf   = (_Float16*)take((size_t)3 * 8 * LMAXc * 512 * 2);     // 24 MB
    int*      flags  = (int*)take(256 * sizeof(int));
    float*    stats  = (float*)take(1024);
    float*    c2     = (float*)take((size_t)4 * 32 * 128 * 4);

    // weight preps (prepw2 also zeroes flags for this launch)
    k_prepw1<<<(4 * 256 * 128 + 255) / 256, 256, 0, stream>>>(l1Wih0, l1Whh0, l1Wih, l1Whh, wcomb1);
    k_prepw2<<<(2 * 4 * 512 * 128 + 255) / 256, 256, 0, stream>>>(l2Wih0, l2Wih, l2Whh0, l2Whh, wih16, whh16, flags);

    // LSTM1: embed + 4 layers fused
    k_scan1all<<<Ntot / 32, 256, 0, stream>>>(atoms, embw, wcomb1, l1b0, l1b, seq1f, dacc);

    k_bn2_stats<<<32, 256, 0, stream>>>(lens, dacc, stats);
    k_bn2_apply<<<(R2c * 128 + 255) / 256, 256, 0, stream>>>(dacc, stats, lens, bn2g, bn2b, seqA);

    // LSTM2: all 4 layers wavefront-pipelined in one kernel
    k_scan2p<<<32, 512, 0, stream>>>(seqA, wih16, whh16, l2b0, l2b, hbuf, flags, c2);

    k_head<<<1, 256, 0, stream>>>(c2, bn3g, bn3b, w1, b1, w2, b2, w22, b22,
                                  w3, b3, w4, b4, w5, b5, out);

    (void)in_sizes; (void)n_in; (void)out_size; (void)ws_size;
}

// Round 2
// 1738.583 us; speedup vs baseline: 2.0080x; 1.0443x over previous
//
#include <hip/hip_runtime.h>

// Round 15: fix k_scan2p's two step-cost pathologies.
//  1) Weights were rematerialized from L2 every step (VGPR_Count=96 < the 128
//     VGPRs the weight set needs). Now loaded via asm volatile global_load ->
//     compiler must keep them VGPR-resident; no compiler VMEM in the loop.
//  2) ph3's vmcnt(0) drained 1-step-old sc0sc1 ops (~900cy latency vs ~400cy
//     slack). Now: fixed 4-VMEM-ops/step pattern (flagstore, xload, hstore,
//     flagload; uniform for ALL layers via dummy-flag region for l0 and an
//     unread hbuf slot for l3) + counted s_waitcnt vmcnt(4) -> every coherent
//     op gets 2 full steps of slack. x/flag prefetch depth 2 with even/odd
//     register rotation; flag publish delayed one step (value t-1).
//  Also: split accumulators accX(bias+Wih*x)/accH(Whh*h) halve the MFMA dep
//  chain 8->4. Everything else unchanged from R14.

typedef _Float16 f16x8  __attribute__((ext_vector_type(8)));
typedef float    f32x4  __attribute__((ext_vector_type(4)));

#define DEVI static __device__ __forceinline__

constexpr int   T1c   = 20;
constexpr int   EMBc  = 32;
constexpr int   H1c   = 64;
constexpr int   LMAXc = 1024;
constexpr int   VOCABc= 85;
constexpr int   Ntot  = 24832;           // sum of lengths
constexpr int   NTc   = Ntot * T1c;      // 496640
constexpr int   R2c   = 32 * LMAXc;      // 32768
constexpr float EPSc  = 1e-5f;

DEVI float sigm(float x)   { return 1.f / (1.f + __expf(-x)); }
DEVI float tanhf_(float x) { return 1.f - 2.f / (1.f + __expf(2.f * x)); }

DEVI void barrier_lds() {                // barrier draining LDS only (not vmcnt)
    asm volatile("s_waitcnt lgkmcnt(0)\n\ts_barrier" ::: "memory");
}
DEVI void drain_vmem() {
    asm volatile("s_waitcnt vmcnt(0)" ::: "memory");
}

// ---------------- prep: LSTM1 combined fp16 [4][256][128] = [Wih|pad|Whh]
__global__ void __launch_bounds__(256)
k_prepw1(const float* __restrict__ Wih0, const float* __restrict__ Whh0,
         const float* __restrict__ WihS, const float* __restrict__ WhhS,
         _Float16* __restrict__ out)
{
    int i = blockIdx.x * 256 + threadIdx.x;
    if (i >= 4 * 256 * 128) return;
    int l = i >> 15, rem = i & 32767, r = rem >> 7, k = rem & 127;
    float v;
    if (l == 0) {
        if (k < 32)      v = Wih0[r * 32 + k];
        else if (k < 64) v = 0.f;
        else             v = Whh0[r * 64 + (k - 64)];
    } else {
        if (k < 64)      v = WihS[((l - 1) * 256 + r) * 64 + k];
        else             v = WhhS[((l - 1) * 256 + r) * 64 + (k - 64)];
    }
    out[i] = (_Float16)v;
}

// ---------------- prep: LSTM2 wih16 [4][512][128] (l0 zero-padded) + whh16
// also resets pipeline flags: [0..255] real -> 0, [256..511] dummy -> INT_MAX
__global__ void __launch_bounds__(256)
k_prepw2(const float* __restrict__ Wih0, const float* __restrict__ WihS,
         const float* __restrict__ Whh0, const float* __restrict__ WhhS,
         _Float16* __restrict__ wih, _Float16* __restrict__ whh,
         int* __restrict__ flags)
{
    int i = blockIdx.x * 256 + threadIdx.x;
    if (i < 512) flags[i] = (i < 256) ? 0 : 0x7fffffff;
    if (i >= 2 * 4 * 512 * 128) return;
    int half = i >> 18, rem = i & 262143;
    int l = rem >> 16, r = (rem >> 7) & 511, k = rem & 127;
    if (half == 0) {
        float v = (l == 0) ? ((k < 64) ? Wih0[r * 64 + k] : 0.f)
                           : WihS[((l - 1) * 512 + r) * 128 + k];
        wih[rem] = (_Float16)v;
    } else {
        float v = (l == 0) ? Whh0[r * 128 + k]
                           : WhhS[((l - 1) * 512 + r) * 128 + k];
        whh[rem] = (_Float16)v;
    }
}

// ---------------- LSTM1: embed + 4 layers fused, one kernel. 32 samples/WG,
// 256 thr = 4 waves. Uniform K=128 body ([x(64, l0 zero-padded)|h(64)]).
__global__ void __launch_bounds__(256)
k_scan1all(const int* __restrict__ atoms, const float* __restrict__ ew,
           const _Float16* __restrict__ W16all,
           const float* __restrict__ b0, const float* __restrict__ bS,
           _Float16* __restrict__ seq, float* __restrict__ dacc)
{
    constexpr int SX = 136;
    __shared__ alignas(16) _Float16 xh[32 * SX];     // 8.7 KB
    __shared__ float ewl[VOCABc * EMBc];             // 10.9 KB
    __shared__ int   aidl[32 * T1c];                 // 2.5 KB

    const int tid  = threadIdx.x;
    const int lane = tid & 63;
    const int wv   = tid >> 6;
    const int l16  = lane & 15;
    const int quad = lane >> 4;
    const int n0   = blockIdx.x * 32;
    const int d    = wv * 16 + l16;

    for (int i = tid; i < VOCABc * EMBc; i += 256) ewl[i] = ew[i];
    for (int i = tid; i < 32 * T1c; i += 256) aidl[i] = atoms[n0 * T1c + i];

    float daccv[2][4];
#pragma unroll
    for (int mt = 0; mt < 2; ++mt)
#pragma unroll
        for (int r = 0; r < 4; ++r) daccv[mt][r] = 0.f;

    __syncthreads();

#pragma unroll 1
    for (int l = 0; l < 4; ++l) {
        const _Float16* W16  = W16all + (size_t)l * 256 * 128;
        const float*    bptr = (l == 0) ? b0 : bS + (l - 1) * 256;

        float bias[4];
#pragma unroll
        for (int g = 0; g < 4; ++g) bias[g] = bptr[g * 64 + d];

        f16x8 wF[4][4];
#pragma unroll
        for (int kc = 0; kc < 4; ++kc) {
            const int kb = kc * 32 + quad * 8;
#pragma unroll
            for (int g = 0; g < 4; ++g)
                wF[kc][g] = *(const f16x8*)&W16[(size_t)(g * 64 + d) * 128 + kb];
        }

        f32x4 c[2];
        c[0] = {1.f, 1.f, 1.f, 1.f};
        c[1] = {1.f, 1.f, 1.f, 1.f};

        drain_vmem();            // prev layer's seq stores complete (same CU)
        __syncthreads();

        // h(t=-1) = 1; layer 0: zero x cols [32,64) once (zero weights there)
#pragma unroll
        for (int mt = 0; mt < 2; ++mt)
#pragma unroll
            for (int r = 0; r < 4; ++r)
                xh[(mt * 16 + quad * 4 + r) * SX + 64 + d] = (_Float16)1.0f;
        if (l == 0)
            for (int idx = tid; idx < 32 * 32; idx += 256) {
                int s = idx >> 5, e = idx & 31;
                xh[s * SX + 32 + e] = (_Float16)0.f;
            }

#pragma unroll 1
        for (int t = 0; t < T1c; ++t) {
            if (l == 0) {
                for (int idx = tid; idx < 32 * 32; idx += 256) {
                    int s = idx >> 5, e = idx & 31;
                    int id = aidl[s * T1c + t];
                    xh[s * SX + e] = (_Float16)(ewl[id * EMBc + e] * (float)id);
                }
            } else {
                for (int idx = tid; idx < 32 * 8; idx += 256) {
                    int s = idx >> 3, k8 = idx & 7;
                    *(f16x8*)&xh[s * SX + k8 * 8] =
                        *(const f16x8*)&seq[((size_t)(n0 + s) * T1c + t) * H1c + k8 * 8];
                }
            }
            __syncthreads();

            f32x4 acc[2][4];
#pragma unroll
            for (int mt = 0; mt < 2; ++mt)
#pragma unroll
                for (int g = 0; g < 4; ++g)
                    acc[mt][g] = {bias[g], bias[g], bias[g], bias[g]};

#pragma unroll
            for (int kc = 0; kc < 4; ++kc) {
                const int kb = kc * 32 + quad * 8;
                f16x8 ah[2];
#pragma unroll
                for (int mt = 0; mt < 2; ++mt)
                    ah[mt] = *(const f16x8*)&xh[(mt * 16 + l16) * SX + kb];
#pragma unroll
                for (int g = 0; g < 4; ++g)
#pragma unroll
                    for (int mt = 0; mt < 2; ++mt)
                        acc[mt][g] = __builtin_amdgcn_mfma_f32_16x16x32_f16(ah[mt], wF[kc][g], acc[mt][g], 0, 0, 0);
            }
            __syncthreads();

#pragma unroll
            for (int mt = 0; mt < 2; ++mt)
#pragma unroll
                for (int r = 0; r < 4; ++r) {
                    float iv = sigm(acc[mt][0][r]);
                    float fv = sigm(acc[mt][1][r]);
                    float gv = tanhf_(acc[mt][2][r]);
                    float ov = sigm(acc[mt][3][r]);
                    float cv = fv * c[mt][r] + iv * gv;
                    c[mt][r] = cv;
                    float hv = ov * tanhf_(cv);
                    _Float16 hf = (_Float16)hv;
                    int s = mt * 16 + quad * 4 + r;
                    xh[s * SX + 64 + d] = hf;
                    if (l < 3)
                        seq[((size_t)(n0 + s) * T1c + t) * H1c + d] = hf;
                    if (t == T1c - 1)
                        daccv[mt][r] += 0.25f * (hv + cv);
                }
        }
    }
#pragma unroll
    for (int mt = 0; mt < 2; ++mt)
#pragma unroll
        for (int r = 0; r < 4; ++r) {
            int s = mt * 16 + quad * 4 + r;
            dacc[(size_t)(n0 + s) * H1c + d] = daccv[mt][r];
        }
}

// ---------------- BN2 stats
__global__ void __launch_bounds__(256)
k_bn2_stats(const int* __restrict__ lens, const float* __restrict__ dacc,
            float* __restrict__ stats)
{
    int b = blockIdx.x;
    int off = 0;
    for (int i = 0; i < b; ++i) off += lens[i];
    int len = lens[b];
    const float* base = dacc + (long)off * H1c;
    float s = 0.f, ss = 0.f;
    int total = len * H1c;
    for (int i = threadIdx.x; i < total; i += 256) { float v = base[i]; s += v; ss += v * v; }
    __shared__ float rs[256], rss[256];
    rs[threadIdx.x] = s; rss[threadIdx.x] = ss;
    __syncthreads();
    for (int st = 128; st > 0; st >>= 1) {
        if (threadIdx.x < st) { rs[threadIdx.x] += rs[threadIdx.x + st]; rss[threadIdx.x] += rss[threadIdx.x + st]; }
        __syncthreads();
    }
    if (threadIdx.x == 0) {
        float m = rs[0] / (float)(LMAXc * H1c);
        float v = rss[0] / (float)(LMAXc * H1c) - m * m;
        stats[b]      = m;
        stats[32 + b] = rsqrtf(fmaxf(v, 0.f) + EPSc);
        stats[64 + b] = (float)off;
    }
}

// ---------------- BN2 apply -> LSTM2 layer-0 input, fp16, rows (t*32+b) of 128
__global__ void __launch_bounds__(256)
k_bn2_apply(const float* __restrict__ dacc, const float* __restrict__ stats,
            const int* __restrict__ lens, const float* __restrict__ g,
            const float* __restrict__ bb, _Float16* __restrict__ outA)
{
    int i = blockIdx.x * 256 + threadIdx.x;
    if (i >= R2c * 128) return;
    int rr = i >> 7, k = i & 127;
    int b = rr >> 10, p = rr & 1023;
    float y = 0.f;
    if (k < H1c) {
        int off = (int)stats[64 + b];
        float x = (p < lens[b]) ? dacc[(off + p) * H1c + k] : 0.f;
        y = (x - stats[b]) * stats[32 + b] * g[b] + bb[b];
    }
    outA[(size_t)(p * 32 + b) * 128 + k] = (_Float16)y;
}

DEVI float qsel(f32x4 a, int quad) {     // a[quad] via cndmask
    float t01 = (quad & 1) ? a[1] : a[0];
    float t23 = (quad & 1) ? a[3] : a[2];
    return (quad & 2) ? t23 : t01;
}

// fresh spin on 8 per-wave producer flags (lanes 0..7 each watch one flag).
// Contains vmcnt(0): over-drains the counted window -> always safe.
DEVI void spin_ge(const int* fl, int lane, int need)
{
    for (;;) {
        int f = 0x7fffffff;
        if (lane < 8)
            asm volatile("global_load_dword %0, %1, off sc0 sc1\n\ts_waitcnt vmcnt(0)"
                         : "+v"(f) : "v"(fl) : "memory");
        if (__all(f >= need)) break;
    }
}

// ---------------- LSTM2: all 4 layers, wavefront-pipelined across blocks.
// 32 blocks = (layer l = bx&3) x (sample group g = bx>>2, 4 samples each).
// Per step, per wave, EXACTLY 4 VMEM ops in order [flagstore, xload, hstore,
// flagload]; ph3's s_waitcnt vmcnt(4) drains the ops issued 2 steps ago ->
// ~2 steps of slack vs ~900cy coherent latency = zero stall. Weights/bias
// loaded via asm (VGPR-resident, no compiler VMEM in loop).
#define STEP(T, PAR, R, F)                                                          \
  {                                                                                 \
    f32x4 accX[4], accH[4];                                                         \
    _Pragma("unroll") for (int g4 = 0; g4 < 4; ++g4) {                              \
        accX[g4] = {bia[g4], bia[g4], bia[g4], bia[g4]};                            \
        accH[g4] = {0.f, 0.f, 0.f, 0.f};                                            \
    }                                                                               \
    _Pragma("unroll") for (int kc = 0; kc < 4; ++kc) {                              \
        f16x8 ax = *(const f16x8*)&xp[PAR][(l16 & 3) * SH + kc * 32 + quad * 8];    \
        _Pragma("unroll") for (int g4 = 0; g4 < 4; ++g4)                            \
            accX[g4] = __builtin_amdgcn_mfma_f32_16x16x32_f16(ax, wI[g4][kc], accX[g4], 0, 0, 0); \
    }                                                                               \
    _Pragma("unroll") for (int kc = 0; kc < 4; ++kc) {                              \
        f16x8 ah = *(const f16x8*)&av[PAR][(l16 & 3) * SH + kc * 32 + quad * 8];    \
        _Pragma("unroll") for (int g4 = 0; g4 < 4; ++g4)                            \
            accH[g4] = __builtin_amdgcn_mfma_f32_16x16x32_f16(ah, wH[g4][kc], accH[g4], 0, 0, 0); \
    }                                                                               \
    asm volatile("s_waitcnt vmcnt(4)" ::: "memory");                                \
    __builtin_amdgcn_sched_barrier(0);                                              \
    if (lane == 0) {                                                                \
        int fv = (T) - 1;                                                           \
        asm volatile("global_store_dword %0, %1, off sc0 sc1"                       \
                     :: "v"(myflag), "v"(fv) : "memory");                           \
    }                                                                               \
    *(unsigned*)&xp[PAR ^ 1][csam * SH + 2 * coff] = R;                             \
    float gi = qsel(accX[0], quad) + qsel(accH[0], quad);                           \
    float gf = qsel(accX[1], quad) + qsel(accH[1], quad);                           \
    float gg = qsel(accX[2], quad) + qsel(accH[2], quad);                           \
    float go = qsel(accX[3], quad) + qsel(accH[3], quad);                           \
    float cv = sigm(gf) * cst + sigm(gi) * tanhf_(gg);                              \
    cst = cv;                                                                       \
    float hv = sigm(go) * tanhf_(cv);                                               \
    _Float16 hf = (_Float16)hv;                                                     \
    av[PAR ^ 1][quad * SH + cell] = hf;                                             \
    {                                                                               \
        int need = ((T) <= LMAXc - 4) ? (T) + 4 : 0;                                \
        if (!__all(lane >= 8 || F >= need)) spin_ge(sflag, lane, need);             \
    }                                                                               \
    if (l == 0)                                                                     \
        asm volatile("global_load_dword %0, %1, off" : "=v"(R) : "v"(xq) : "memory"); \
    else                                                                            \
        asm volatile("global_load_dword %0, %1, off sc0 sc1" : "=v"(R) : "v"(xq) : "memory"); \
    if ((T) < LMAXc - 4) xq += xstep;                                               \
    {   unsigned hb = (unsigned)__builtin_bit_cast(unsigned short, hf);             \
        asm volatile("global_store_short %0, %1, off sc0 sc1"                       \
                     :: "v"(hp), "v"(hb) : "memory"); }                             \
    hp += 512;                                                                      \
    if (lane < 8)                                                                   \
        asm volatile("global_load_dword %0, %1, off sc0 sc1"                        \
                     : "+v"(F) : "v"(sflag) : "memory");                            \
    barrier_lds();                                                                  \
  }

__global__ void __launch_bounds__(512, 2)
k_scan2p(const _Float16* __restrict__ seqA,   // [32768][128] l0 input
         const _Float16* __restrict__ wihAll, // [4][512][128] fp16
         const _Float16* __restrict__ whhAll, // [4][512][128] fp16
         const float* __restrict__ b0,        // [512]
         const float* __restrict__ bS,        // [3][512]
         _Float16* __restrict__ hbuf,         // [4][8][1024*512] fp16 (slot 3 unread)
         int* __restrict__ flags,             // [512]
         float* __restrict__ c2)              // [4][32][128]
{
    constexpr int SH = 144;
    __shared__ alignas(16) _Float16 av[2][4 * SH];   // h(t-1) double buffer
    __shared__ alignas(16) _Float16 xp[2][4 * SH];   // x(t) double buffer

    const int bx   = blockIdx.x;
    const int l    = bx & 3;
    const int g    = bx >> 2;
    const int tid  = threadIdx.x;
    const int lane = tid & 63;
    const int w    = tid >> 6;
    const int l16  = lane & 15;
    const int quad = lane >> 4;
    const int cell = w * 16 + l16;

    const _Float16* Wih = wihAll + (size_t)l * 512 * 128;
    const _Float16* Whh = whhAll + (size_t)l * 512 * 128;
    const float*   bptr = (l == 0) ? b0 : bS + (l - 1) * 512;

    // weights + bias via volatile asm -> compiler cannot rematerialize; they
    // stay VGPR-resident (160 VGPR) for the whole scan.
    f16x8 wI[4][4], wH[4][4];
    float bia[4];
#pragma unroll
    for (int g4 = 0; g4 < 4; ++g4) {
#pragma unroll
        for (int kc = 0; kc < 4; ++kc) {
            const _Float16* pI = &Wih[(size_t)(g4 * 128 + cell) * 128 + kc * 32 + quad * 8];
            const _Float16* pH = &Whh[(size_t)(g4 * 128 + cell) * 128 + kc * 32 + quad * 8];
            asm volatile("global_load_dwordx4 %0, %1, off" : "=v"(wI[g4][kc]) : "v"(pI));
            asm volatile("global_load_dwordx4 %0, %1, off" : "=v"(wH[g4][kc]) : "v"(pH));
        }
        const float* pb = &bptr[g4 * 128 + cell];
        asm volatile("global_load_dword %0, %1, off" : "=v"(bia[g4]) : "v"(pb));
    }
    drain_vmem();
    __builtin_amdgcn_sched_barrier(0);

    // consumer-side x tile: 1KB/step = 256 dwords; all 512 threads load
    // (tid>=256 duplicate) so vmcnt accounting is wave-uniform.
    const int ci   = tid & 255;
    const int csam = ci >> 6;         // sample 0..3
    const int coff = ci & 63;         // dword within 128-fp16 row

    const unsigned* xq;
    int xstep;                        // dwords per t
    if (l == 0) {
        xq    = (const unsigned*)seqA + ((size_t)(g * 4 + csam)) * 64 + coff;
        xstep = 32 * 64;
    } else {
        xq    = (const unsigned*)(hbuf + ((size_t)((l - 1) * 8 + g)) * (LMAXc * 512)) + ci;
        xstep = 256;
    }

    _Float16*  hp     = hbuf + ((size_t)(l * 8 + g)) * (LMAXc * 512) + quad * 128 + cell;
    int*       myflag = flags + (l * 8 + g) * 8 + w;
    const int* sflag  = (l == 0) ? (flags + 256 + (lane & 7))
                                 : (flags + ((l - 1) * 8 + g) * 8 + (lane & 7));

    // init h(-1) = 1, c(-1) = 1
    { int s = tid >> 7, e = tid & 127; av[0][s * SH + e] = (_Float16)1.0f; }
    float cst = 1.f;

    unsigned rA, rB;
    int fpreA = 0, fpreB = 0;

    // prologue: x(0)->LDS, x(1)->rA (drained), x(2)->rB (in flight),
    // 2 flag prefetches in flight. Outstanding at t=0 ph3: 3 -> vmcnt(4) ok.
    spin_ge(sflag, lane, 1);
    if (l == 0) asm volatile("global_load_dword %0, %1, off" : "=v"(rA) : "v"(xq) : "memory");
    else        asm volatile("global_load_dword %0, %1, off sc0 sc1" : "=v"(rA) : "v"(xq) : "memory");
    drain_vmem();
    __builtin_amdgcn_sched_barrier(0);
    *(unsigned*)&xp[0][csam * SH + 2 * coff] = rA;

    spin_ge(sflag, lane, 2);
    {
        const unsigned* p1 = xq + xstep;
        if (l == 0) asm volatile("global_load_dword %0, %1, off" : "=v"(rA) : "v"(p1) : "memory");
        else        asm volatile("global_load_dword %0, %1, off sc0 sc1" : "=v"(rA) : "v"(p1) : "memory");
    }
    drain_vmem();
    __builtin_amdgcn_sched_barrier(0);

    spin_ge(sflag, lane, 3);
    {
        const unsigned* p2 = xq + 2 * xstep;
        if (l == 0) asm volatile("global_load_dword %0, %1, off" : "=v"(rB) : "v"(p2) : "memory");
        else        asm volatile("global_load_dword %0, %1, off sc0 sc1" : "=v"(rB) : "v"(p2) : "memory");
    }
    if (lane < 8) {
        asm volatile("global_load_dword %0, %1, off sc0 sc1" : "+v"(fpreA) : "v"(sflag) : "memory");
        asm volatile("global_load_dword %0, %1, off sc0 sc1" : "+v"(fpreB) : "v"(sflag) : "memory");
    }
    xq += 3 * (size_t)xstep;          // -> x(3), target of step 0's prefetch
    __syncthreads();

#pragma unroll 1
    for (int t = 0; t < LMAXc; t += 2) {
        STEP(t,     0, rA, fpreA)
        STEP(t + 1, 1, rB, fpreB)
    }

    // epilogue: drain everything, publish final flag = LMAX
    drain_vmem();
    if (lane == 0) {
        int fin = LMAXc;
        asm volatile("global_store_dword %0, %1, off sc0 sc1"
                     :: "v"(myflag), "v"(fin) : "memory");
    }
    c2[(size_t)l * 4096 + (g * 4 + quad) * 128 + cell] = 0.25f * cst;
}

// ---------------- head: BN3 + MLP + relu(sum), single WG fp32
DEVI void bn_rows_dev(float* X, int K, const float* g, const float* bb,
                      float* mv, int tid)
{
    __syncthreads();
    if (tid < 32) {
        float s = 0.f, ss = 0.f;
        const float* r = X + tid * K;
        for (int k = 0; k < K; ++k) { float v = r[k]; s += v; ss += v * v; }
        float m = s / (float)K;
        float vv = ss / (float)K - m * m;
        mv[tid]      = m;
        mv[32 + tid] = rsqrtf(fmaxf(vv, 0.f) + EPSc);
    }
    __syncthreads();
    for (int i = tid; i < 32 * K; i += 256) {
        int b = i / K;
        X[i] = (X[i] - mv[b]) * mv[32 + b] * g[b] + bb[b];
    }
    __syncthreads();
}

DEVI void lin_dev(const float* X, int K, const float* W, const float* bias,
                  int NO, float* Y, int relu, int tid)
{
    __syncthreads();
    for (int i = tid; i < 32 * NO; i += 256) {
        int b = i / NO, j = i - b * NO;
        float a = bias[j];
        const float* xr = X + b * K;
        const float* wr = W + j * K;
        for (int k = 0; k < K; ++k) a += xr[k] * wr[k];
        Y[i] = relu ? fmaxf(a, 0.f) : a;
    }
    __syncthreads();
}

__global__ void __launch_bounds__(256)
k_head(const float* __restrict__ c2, const float* __restrict__ g3, const float* __restrict__ bb3,
       const float* w1, const float* b1, const float* w2, const float* b2,
       const float* w22, const float* b22, const float* w3, const float* b3,
       const float* w4, const float* b4, const float* w5, const float* b5,
       float* __restrict__ out)
{
    __shared__ float A[32 * 128];
    __shared__ float Bf[32 * 128];
    __shared__ float mv[64];
    const int tid = threadIdx.x;

    for (int i = tid; i < 32 * 128; i += 256)
        A[i] = c2[i] + c2[4096 + i] + c2[8192 + i] + c2[12288 + i];
    bn_rows_dev(A, 128, g3, bb3, mv, tid);
    lin_dev(A, 128, w1, b1, 128, Bf, 1, tid);
    lin_dev(Bf, 128, w2, b2, 64, A, 1, tid);
    bn_rows_dev(A, 64, g3, bb3, mv, tid);
    lin_dev(A, 64, w22, b22, 64, Bf, 1, tid);
    lin_dev(Bf, 64, w3, b3, 32, A, 1, tid);
    lin_dev(A, 32, w4, b4, 32, Bf, 1, tid);
    lin_dev(Bf, 32, w5, b5, 16, A, 0, tid);
    if (tid < 32) {
        float s = 0.f;
        for (int j = 0; j < 16; ++j) s += A[tid * 16 + j];
        out[tid] = fmaxf(s, 0.f);
    }
}

// ---------------- host
extern "C" void kernel_launch(void* const* d_in, const int* in_sizes, int n_in,
                              void* d_out, int out_size, void* d_ws, size_t ws_size,
                              hipStream_t stream)
{
    const int*   atoms  = (const int*)d_in[0];
    const int*   lens   = (const int*)d_in[2];
    const float* embw   = (const float*)d_in[5];
    const float* l1Wih0 = (const float*)d_in[6];
    const float* l1Whh0 = (const float*)d_in[7];
    const float* l1b0   = (const float*)d_in[8];
    const float* l1Wih  = (const float*)d_in[9];
    const float* l1Whh  = (const float*)d_in[10];
    const float* l1b    = (const float*)d_in[11];
    const float* l2Wih0 = (const float*)d_in[12];
    const float* l2Whh0 = (const float*)d_in[13];
    const float* l2b0   = (const float*)d_in[14];
    const float* l2Wih  = (const float*)d_in[15];
    const float* l2Whh  = (const float*)d_in[16];
    const float* l2b    = (const float*)d_in[17];
    const float* bn2g   = (const float*)d_in[18];
    const float* bn2b   = (const float*)d_in[19];
    const float* bn3g   = (const float*)d_in[20];
    const float* bn3b   = (const float*)d_in[21];
    const float* w1  = (const float*)d_in[22]; const float* b1  = (const float*)d_in[23];
    const float* w2  = (const float*)d_in[24]; const float* b2  = (const float*)d_in[25];
    const float* w22 = (const float*)d_in[26]; const float* b22 = (const float*)d_in[27];
    const float* w3  = (const float*)d_in[28]; const float* b3  = (const float*)d_in[29];
    const float* w4  = (const float*)d_in[30]; const float* b4  = (const float*)d_in[31];
    const float* w5  = (const float*)d_in[32]; const float* b5  = (const float*)d_in[33];
    float* out = (float*)d_out;

    char* base = (char*)d_ws;
    size_t off = 0;
    auto take = [&](size_t bytes) -> char* {
        char* p = base + off;
        off = (off + bytes + 255) & ~(size_t)255;
        return p;
    };
    _Float16* seq1f  = (_Float16*)take((size_t)NTc * H1c * 2);               // 63.6 MB
    float*    dacc   = (float*)take((size_t)Ntot * H1c * 4);                 // 6.4 MB
    _Float16* wcomb1 = (_Float16*)take((size_t)4 * 256 * 128 * 2);           // 256 KB
    _Float16* wih16  = (_Float16*)take((size_t)4 * 512 * 128 * 2);           // 512 KB
    _Float16* whh16  = (_Float16*)take((size_t)4 * 512 * 128 * 2);           // 512 KB
    _Float16* seqA   = (_Float16*)take((size_t)R2c * 128 * 2);               // 8.4 MB
    _Float16* hbuf   = (_Float16*)take((size_t)4 * 8 * LMAXc * 512 * 2);     // 32 MB
    int*      flags  = (int*)take(512 * sizeof(int));
    float*    stats  = (float*)take(1024);
    float*    c2     = (float*)take((size_t)4 * 32 * 128 * 4);

    // weight preps (prepw2 also resets flags for this launch)
    k_prepw1<<<(4 * 256 * 128 + 255) / 256, 256, 0, stream>>>(l1Wih0, l1Whh0, l1Wih, l1Whh, wcomb1);
    k_prepw2<<<(2 * 4 * 512 * 128 + 255) / 256, 256, 0, stream>>>(l2Wih0, l2Wih, l2Whh0, l2Whh, wih16, whh16, flags);

    // LSTM1: embed + 4 layers fused
    k_scan1all<<<Ntot / 32, 256, 0, stream>>>(atoms, embw, wcomb1, l1b0, l1b, seq1f, dacc);

    k_bn2_stats<<<32, 256, 0, stream>>>(lens, dacc, stats);
    k_bn2_apply<<<(R2c * 128 + 255) / 256, 256, 0, stream>>>(dacc, stats, lens, bn2g, bn2b, seqA);

    // LSTM2: all 4 layers wavefront-pipelined in one kernel
    k_scan2p<<<32, 512, 0, stream>>>(seqA, wih16, whh16, l2b0, l2b, hbuf, flags, c2);

    k_head<<<1, 256, 0, stream>>>(c2, bn3g, bn3b, w1, b1, w2, b2, w22, b22,
                                  w3, b3, w4, b4, w5, b5, out);

    (void)in_sizes; (void)n_in; (void)out_size; (void)ws_size;
}

// Round 3
// 1730.007 us; speedup vs baseline: 2.0179x; 1.0050x over previous
//
#include <hip/hip_runtime.h>

// Round 16: un-spill k_scan2p's weights (one-attribute fix).
//  R15 evidence: VGPR_Count=108 < 128 (weight set size) and WRITE_SIZE
//  +10MB = one-time scratch spill of the weights; every step then reloaded
//  512B/thread from scratch -> ~2000cy/step L1-BW-bound. Cause:
//  __launch_bounds__(512,2) gave the allocator a 128-VGPR budget.
//  Fix: amdgpu_flat_work_group_size(512,512) + amdgpu_waves_per_eu(2,2)
//  -> 256-VGPR budget, weights stay VGPR-resident. Everything else is
//  unchanged from R15 (counted vmcnt(4) window, 4 uniform VMEM ops/step,
//  split accX/accH, asm-loaded weights).

typedef _Float16 f16x8  __attribute__((ext_vector_type(8)));
typedef float    f32x4  __attribute__((ext_vector_type(4)));

#define DEVI static __device__ __forceinline__

constexpr int   T1c   = 20;
constexpr int   EMBc  = 32;
constexpr int   H1c   = 64;
constexpr int   LMAXc = 1024;
constexpr int   VOCABc= 85;
constexpr int   Ntot  = 24832;           // sum of lengths
constexpr int   NTc   = Ntot * T1c;      // 496640
constexpr int   R2c   = 32 * LMAXc;      // 32768
constexpr float EPSc  = 1e-5f;

DEVI float sigm(float x)   { return 1.f / (1.f + __expf(-x)); }
DEVI float tanhf_(float x) { return 1.f - 2.f / (1.f + __expf(2.f * x)); }

DEVI void barrier_lds() {                // barrier draining LDS only (not vmcnt)
    asm volatile("s_waitcnt lgkmcnt(0)\n\ts_barrier" ::: "memory");
}
DEVI void drain_vmem() {
    asm volatile("s_waitcnt vmcnt(0)" ::: "memory");
}

// ---------------- prep: LSTM1 combined fp16 [4][256][128] = [Wih|pad|Whh]
__global__ void __launch_bounds__(256)
k_prepw1(const float* __restrict__ Wih0, const float* __restrict__ Whh0,
         const float* __restrict__ WihS, const float* __restrict__ WhhS,
         _Float16* __restrict__ out)
{
    int i = blockIdx.x * 256 + threadIdx.x;
    if (i >= 4 * 256 * 128) return;
    int l = i >> 15, rem = i & 32767, r = rem >> 7, k = rem & 127;
    float v;
    if (l == 0) {
        if (k < 32)      v = Wih0[r * 32 + k];
        else if (k < 64) v = 0.f;
        else             v = Whh0[r * 64 + (k - 64)];
    } else {
        if (k < 64)      v = WihS[((l - 1) * 256 + r) * 64 + k];
        else             v = WhhS[((l - 1) * 256 + r) * 64 + (k - 64)];
    }
    out[i] = (_Float16)v;
}

// ---------------- prep: LSTM2 wih16 [4][512][128] (l0 zero-padded) + whh16
// also resets pipeline flags: [0..255] real -> 0, [256..511] dummy -> INT_MAX
__global__ void __launch_bounds__(256)
k_prepw2(const float* __restrict__ Wih0, const float* __restrict__ WihS,
         const float* __restrict__ Whh0, const float* __restrict__ WhhS,
         _Float16* __restrict__ wih, _Float16* __restrict__ whh,
         int* __restrict__ flags)
{
    int i = blockIdx.x * 256 + threadIdx.x;
    if (i < 512) flags[i] = (i < 256) ? 0 : 0x7fffffff;
    if (i >= 2 * 4 * 512 * 128) return;
    int half = i >> 18, rem = i & 262143;
    int l = rem >> 16, r = (rem >> 7) & 511, k = rem & 127;
    if (half == 0) {
        float v = (l == 0) ? ((k < 64) ? Wih0[r * 64 + k] : 0.f)
                           : WihS[((l - 1) * 512 + r) * 128 + k];
        wih[rem] = (_Float16)v;
    } else {
        float v = (l == 0) ? Whh0[r * 128 + k]
                           : WhhS[((l - 1) * 512 + r) * 128 + k];
        whh[rem] = (_Float16)v;
    }
}

// ---------------- LSTM1: embed + 4 layers fused, one kernel. 32 samples/WG,
// 256 thr = 4 waves. Uniform K=128 body ([x(64, l0 zero-padded)|h(64)]).
__global__ void __launch_bounds__(256)
k_scan1all(const int* __restrict__ atoms, const float* __restrict__ ew,
           const _Float16* __restrict__ W16all,
           const float* __restrict__ b0, const float* __restrict__ bS,
           _Float16* __restrict__ seq, float* __restrict__ dacc)
{
    constexpr int SX = 136;
    __shared__ alignas(16) _Float16 xh[32 * SX];     // 8.7 KB
    __shared__ float ewl[VOCABc * EMBc];             // 10.9 KB
    __shared__ int   aidl[32 * T1c];                 // 2.5 KB

    const int tid  = threadIdx.x;
    const int lane = tid & 63;
    const int wv   = tid >> 6;
    const int l16  = lane & 15;
    const int quad = lane >> 4;
    const int n0   = blockIdx.x * 32;
    const int d    = wv * 16 + l16;

    for (int i = tid; i < VOCABc * EMBc; i += 256) ewl[i] = ew[i];
    for (int i = tid; i < 32 * T1c; i += 256) aidl[i] = atoms[n0 * T1c + i];

    float daccv[2][4];
#pragma unroll
    for (int mt = 0; mt < 2; ++mt)
#pragma unroll
        for (int r = 0; r < 4; ++r) daccv[mt][r] = 0.f;

    __syncthreads();

#pragma unroll 1
    for (int l = 0; l < 4; ++l) {
        const _Float16* W16  = W16all + (size_t)l * 256 * 128;
        const float*    bptr = (l == 0) ? b0 : bS + (l - 1) * 256;

        float bias[4];
#pragma unroll
        for (int g = 0; g < 4; ++g) bias[g] = bptr[g * 64 + d];

        f16x8 wF[4][4];
#pragma unroll
        for (int kc = 0; kc < 4; ++kc) {
            const int kb = kc * 32 + quad * 8;
#pragma unroll
            for (int g = 0; g < 4; ++g)
                wF[kc][g] = *(const f16x8*)&W16[(size_t)(g * 64 + d) * 128 + kb];
        }

        f32x4 c[2];
        c[0] = {1.f, 1.f, 1.f, 1.f};
        c[1] = {1.f, 1.f, 1.f, 1.f};

        drain_vmem();            // prev layer's seq stores complete (same CU)
        __syncthreads();

        // h(t=-1) = 1; layer 0: zero x cols [32,64) once (zero weights there)
#pragma unroll
        for (int mt = 0; mt < 2; ++mt)
#pragma unroll
            for (int r = 0; r < 4; ++r)
                xh[(mt * 16 + quad * 4 + r) * SX + 64 + d] = (_Float16)1.0f;
        if (l == 0)
            for (int idx = tid; idx < 32 * 32; idx += 256) {
                int s = idx >> 5, e = idx & 31;
                xh[s * SX + 32 + e] = (_Float16)0.f;
            }

#pragma unroll 1
        for (int t = 0; t < T1c; ++t) {
            if (l == 0) {
                for (int idx = tid; idx < 32 * 32; idx += 256) {
                    int s = idx >> 5, e = idx & 31;
                    int id = aidl[s * T1c + t];
                    xh[s * SX + e] = (_Float16)(ewl[id * EMBc + e] * (float)id);
                }
            } else {
                for (int idx = tid; idx < 32 * 8; idx += 256) {
                    int s = idx >> 3, k8 = idx & 7;
                    *(f16x8*)&xh[s * SX + k8 * 8] =
                        *(const f16x8*)&seq[((size_t)(n0 + s) * T1c + t) * H1c + k8 * 8];
                }
            }
            __syncthreads();

            f32x4 acc[2][4];
#pragma unroll
            for (int mt = 0; mt < 2; ++mt)
#pragma unroll
                for (int g = 0; g < 4; ++g)
                    acc[mt][g] = {bias[g], bias[g], bias[g], bias[g]};

#pragma unroll
            for (int kc = 0; kc < 4; ++kc) {
                const int kb = kc * 32 + quad * 8;
                f16x8 ah[2];
#pragma unroll
                for (int mt = 0; mt < 2; ++mt)
                    ah[mt] = *(const f16x8*)&xh[(mt * 16 + l16) * SX + kb];
#pragma unroll
                for (int g = 0; g < 4; ++g)
#pragma unroll
                    for (int mt = 0; mt < 2; ++mt)
                        acc[mt][g] = __builtin_amdgcn_mfma_f32_16x16x32_f16(ah[mt], wF[kc][g], acc[mt][g], 0, 0, 0);
            }
            __syncthreads();

#pragma unroll
            for (int mt = 0; mt < 2; ++mt)
#pragma unroll
                for (int r = 0; r < 4; ++r) {
                    float iv = sigm(acc[mt][0][r]);
                    float fv = sigm(acc[mt][1][r]);
                    float gv = tanhf_(acc[mt][2][r]);
                    float ov = sigm(acc[mt][3][r]);
                    float cv = fv * c[mt][r] + iv * gv;
                    c[mt][r] = cv;
                    float hv = ov * tanhf_(cv);
                    _Float16 hf = (_Float16)hv;
                    int s = mt * 16 + quad * 4 + r;
                    xh[s * SX + 64 + d] = hf;
                    if (l < 3)
                        seq[((size_t)(n0 + s) * T1c + t) * H1c + d] = hf;
                    if (t == T1c - 1)
                        daccv[mt][r] += 0.25f * (hv + cv);
                }
        }
    }
#pragma unroll
    for (int mt = 0; mt < 2; ++mt)
#pragma unroll
        for (int r = 0; r < 4; ++r) {
            int s = mt * 16 + quad * 4 + r;
            dacc[(size_t)(n0 + s) * H1c + d] = daccv[mt][r];
        }
}

// ---------------- BN2 stats
__global__ void __launch_bounds__(256)
k_bn2_stats(const int* __restrict__ lens, const float* __restrict__ dacc,
            float* __restrict__ stats)
{
    int b = blockIdx.x;
    int off = 0;
    for (int i = 0; i < b; ++i) off += lens[i];
    int len = lens[b];
    const float* base = dacc + (long)off * H1c;
    float s = 0.f, ss = 0.f;
    int total = len * H1c;
    for (int i = threadIdx.x; i < total; i += 256) { float v = base[i]; s += v; ss += v * v; }
    __shared__ float rs[256], rss[256];
    rs[threadIdx.x] = s; rss[threadIdx.x] = ss;
    __syncthreads();
    for (int st = 128; st > 0; st >>= 1) {
        if (threadIdx.x < st) { rs[threadIdx.x] += rs[threadIdx.x + st]; rss[threadIdx.x] += rss[threadIdx.x + st]; }
        __syncthreads();
    }
    if (threadIdx.x == 0) {
        float m = rs[0] / (float)(LMAXc * H1c);
        float v = rss[0] / (float)(LMAXc * H1c) - m * m;
        stats[b]      = m;
        stats[32 + b] = rsqrtf(fmaxf(v, 0.f) + EPSc);
        stats[64 + b] = (float)off;
    }
}

// ---------------- BN2 apply -> LSTM2 layer-0 input, fp16, rows (t*32+b) of 128
__global__ void __launch_bounds__(256)
k_bn2_apply(const float* __restrict__ dacc, const float* __restrict__ stats,
            const int* __restrict__ lens, const float* __restrict__ g,
            const float* __restrict__ bb, _Float16* __restrict__ outA)
{
    int i = blockIdx.x * 256 + threadIdx.x;
    if (i >= R2c * 128) return;
    int rr = i >> 7, k = i & 127;
    int b = rr >> 10, p = rr & 1023;
    float y = 0.f;
    if (k < H1c) {
        int off = (int)stats[64 + b];
        float x = (p < lens[b]) ? dacc[(off + p) * H1c + k] : 0.f;
        y = (x - stats[b]) * stats[32 + b] * g[b] + bb[b];
    }
    outA[(size_t)(p * 32 + b) * 128 + k] = (_Float16)y;
}

DEVI float qsel(f32x4 a, int quad) {     // a[quad] via cndmask
    float t01 = (quad & 1) ? a[1] : a[0];
    float t23 = (quad & 1) ? a[3] : a[2];
    return (quad & 2) ? t23 : t01;
}

// fresh spin on 8 per-wave producer flags (lanes 0..7 each watch one flag).
// Contains vmcnt(0): over-drains the counted window -> always safe.
DEVI void spin_ge(const int* fl, int lane, int need)
{
    for (;;) {
        int f = 0x7fffffff;
        if (lane < 8)
            asm volatile("global_load_dword %0, %1, off sc0 sc1\n\ts_waitcnt vmcnt(0)"
                         : "+v"(f) : "v"(fl) : "memory");
        if (__all(f >= need)) break;
    }
}

// ---------------- LSTM2: all 4 layers, wavefront-pipelined across blocks.
// 32 blocks = (layer l = bx&3) x (sample group g = bx>>2, 4 samples each).
// Per step, per wave, EXACTLY 4 VMEM ops in order [flagstore, xload, hstore,
// flagload]; ph3's s_waitcnt vmcnt(4) drains the ops issued 2 steps ago ->
// ~2 steps of slack vs ~900cy coherent latency = zero stall. Weights/bias
// loaded via asm (VGPR-resident, no compiler VMEM in loop).
#define STEP(T, PAR, R, F)                                                          \
  {                                                                                 \
    f32x4 accX[4], accH[4];                                                         \
    _Pragma("unroll") for (int g4 = 0; g4 < 4; ++g4) {                              \
        accX[g4] = {bia[g4], bia[g4], bia[g4], bia[g4]};                            \
        accH[g4] = {0.f, 0.f, 0.f, 0.f};                                            \
    }                                                                               \
    _Pragma("unroll") for (int kc = 0; kc < 4; ++kc) {                              \
        f16x8 ax = *(const f16x8*)&xp[PAR][(l16 & 3) * SH + kc * 32 + quad * 8];    \
        _Pragma("unroll") for (int g4 = 0; g4 < 4; ++g4)                            \
            accX[g4] = __builtin_amdgcn_mfma_f32_16x16x32_f16(ax, wI[g4][kc], accX[g4], 0, 0, 0); \
    }                                                                               \
    _Pragma("unroll") for (int kc = 0; kc < 4; ++kc) {                              \
        f16x8 ah = *(const f16x8*)&av[PAR][(l16 & 3) * SH + kc * 32 + quad * 8];    \
        _Pragma("unroll") for (int g4 = 0; g4 < 4; ++g4)                            \
            accH[g4] = __builtin_amdgcn_mfma_f32_16x16x32_f16(ah, wH[g4][kc], accH[g4], 0, 0, 0); \
    }                                                                               \
    asm volatile("s_waitcnt vmcnt(4)" ::: "memory");                                \
    __builtin_amdgcn_sched_barrier(0);                                              \
    if (lane == 0) {                                                                \
        int fv = (T) - 1;                                                           \
        asm volatile("global_store_dword %0, %1, off sc0 sc1"                       \
                     :: "v"(myflag), "v"(fv) : "memory");                           \
    }                                                                               \
    *(unsigned*)&xp[PAR ^ 1][csam * SH + 2 * coff] = R;                             \
    float gi = qsel(accX[0], quad) + qsel(accH[0], quad);                           \
    float gf = qsel(accX[1], quad) + qsel(accH[1], quad);                           \
    float gg = qsel(accX[2], quad) + qsel(accH[2], quad);                           \
    float go = qsel(accX[3], quad) + qsel(accH[3], quad);                           \
    float cv = sigm(gf) * cst + sigm(gi) * tanhf_(gg);                              \
    cst = cv;                                                                       \
    float hv = sigm(go) * tanhf_(cv);                                               \
    _Float16 hf = (_Float16)hv;                                                     \
    av[PAR ^ 1][quad * SH + cell] = hf;                                             \
    {                                                                               \
        int need = ((T) <= LMAXc - 4) ? (T) + 4 : 0;                                \
        if (!__all(lane >= 8 || F >= need)) spin_ge(sflag, lane, need);             \
    }                                                                               \
    if (l == 0)                                                                     \
        asm volatile("global_load_dword %0, %1, off" : "=v"(R) : "v"(xq) : "memory"); \
    else                                                                            \
        asm volatile("global_load_dword %0, %1, off sc0 sc1" : "=v"(R) : "v"(xq) : "memory"); \
    if ((T) < LMAXc - 4) xq += xstep;                                               \
    {   unsigned hb = (unsigned)__builtin_bit_cast(unsigned short, hf);             \
        asm volatile("global_store_short %0, %1, off sc0 sc1"                       \
                     :: "v"(hp), "v"(hb) : "memory"); }                             \
    hp += 512;                                                                      \
    if (lane < 8)                                                                   \
        asm volatile("global_load_dword %0, %1, off sc0 sc1"                        \
                     : "+v"(F) : "v"(sflag) : "memory");                            \
    barrier_lds();                                                                  \
  }

__global__ void
__attribute__((amdgpu_flat_work_group_size(512, 512), amdgpu_waves_per_eu(2, 2)))
k_scan2p(const _Float16* __restrict__ seqA,   // [32768][128] l0 input
         const _Float16* __restrict__ wihAll, // [4][512][128] fp16
         const _Float16* __restrict__ whhAll, // [4][512][128] fp16
         const float* __restrict__ b0,        // [512]
         const float* __restrict__ bS,        // [3][512]
         _Float16* __restrict__ hbuf,         // [4][8][1024*512] fp16 (slot 3 unread)
         int* __restrict__ flags,             // [512]
         float* __restrict__ c2)              // [4][32][128]
{
    constexpr int SH = 144;
    __shared__ alignas(16) _Float16 av[2][4 * SH];   // h(t-1) double buffer
    __shared__ alignas(16) _Float16 xp[2][4 * SH];   // x(t) double buffer

    const int bx   = blockIdx.x;
    const int l    = bx & 3;
    const int g    = bx >> 2;
    const int tid  = threadIdx.x;
    const int lane = tid & 63;
    const int w    = tid >> 6;
    const int l16  = lane & 15;
    const int quad = lane >> 4;
    const int cell = w * 16 + l16;

    const _Float16* Wih = wihAll + (size_t)l * 512 * 128;
    const _Float16* Whh = whhAll + (size_t)l * 512 * 128;
    const float*   bptr = (l == 0) ? b0 : bS + (l - 1) * 512;

    // weights + bias via volatile asm -> compiler cannot rematerialize; with
    // the 256-VGPR budget they stay VGPR-resident for the whole scan.
    f16x8 wI[4][4], wH[4][4];
    float bia[4];
#pragma unroll
    for (int g4 = 0; g4 < 4; ++g4) {
#pragma unroll
        for (int kc = 0; kc < 4; ++kc) {
            const _Float16* pI = &Wih[(size_t)(g4 * 128 + cell) * 128 + kc * 32 + quad * 8];
            const _Float16* pH = &Whh[(size_t)(g4 * 128 + cell) * 128 + kc * 32 + quad * 8];
            asm volatile("global_load_dwordx4 %0, %1, off" : "=v"(wI[g4][kc]) : "v"(pI));
            asm volatile("global_load_dwordx4 %0, %1, off" : "=v"(wH[g4][kc]) : "v"(pH));
        }
        const float* pb = &bptr[g4 * 128 + cell];
        asm volatile("global_load_dword %0, %1, off" : "=v"(bia[g4]) : "v"(pb));
    }
    drain_vmem();
    __builtin_amdgcn_sched_barrier(0);

    // consumer-side x tile: 1KB/step = 256 dwords; all 512 threads load
    // (tid>=256 duplicate) so vmcnt accounting is wave-uniform.
    const int ci   = tid & 255;
    const int csam = ci >> 6;         // sample 0..3
    const int coff = ci & 63;         // dword within 128-fp16 row

    const unsigned* xq;
    int xstep;                        // dwords per t
    if (l == 0) {
        xq    = (const unsigned*)seqA + ((size_t)(g * 4 + csam)) * 64 + coff;
        xstep = 32 * 64;
    } else {
        xq    = (const unsigned*)(hbuf + ((size_t)((l - 1) * 8 + g)) * (LMAXc * 512)) + ci;
        xstep = 256;
    }

    _Float16*  hp     = hbuf + ((size_t)(l * 8 + g)) * (LMAXc * 512) + quad * 128 + cell;
    int*       myflag = flags + (l * 8 + g) * 8 + w;
    const int* sflag  = (l == 0) ? (flags + 256 + (lane & 7))
                                 : (flags + ((l - 1) * 8 + g) * 8 + (lane & 7));

    // init h(-1) = 1, c(-1) = 1
    { int s = tid >> 7, e = tid & 127; av[0][s * SH + e] = (_Float16)1.0f; }
    float cst = 1.f;

    unsigned rA, rB;
    int fpreA = 0, fpreB = 0;

    // prologue: x(0)->LDS, x(1)->rA (drained), x(2)->rB (in flight),
    // 2 flag prefetches in flight. Outstanding at t=0 ph3: 3 -> vmcnt(4) ok.
    spin_ge(sflag, lane, 1);
    if (l == 0) asm volatile("global_load_dword %0, %1, off" : "=v"(rA) : "v"(xq) : "memory");
    else        asm volatile("global_load_dword %0, %1, off sc0 sc1" : "=v"(rA) : "v"(xq) : "memory");
    drain_vmem();
    __builtin_amdgcn_sched_barrier(0);
    *(unsigned*)&xp[0][csam * SH + 2 * coff] = rA;

    spin_ge(sflag, lane, 2);
    {
        const unsigned* p1 = xq + xstep;
        if (l == 0) asm volatile("global_load_dword %0, %1, off" : "=v"(rA) : "v"(p1) : "memory");
        else        asm volatile("global_load_dword %0, %1, off sc0 sc1" : "=v"(rA) : "v"(p1) : "memory");
    }
    drain_vmem();
    __builtin_amdgcn_sched_barrier(0);

    spin_ge(sflag, lane, 3);
    {
        const unsigned* p2 = xq + 2 * xstep;
        if (l == 0) asm volatile("global_load_dword %0, %1, off" : "=v"(rB) : "v"(p2) : "memory");
        else        asm volatile("global_load_dword %0, %1, off sc0 sc1" : "=v"(rB) : "v"(p2) : "memory");
    }
    if (lane < 8) {
        asm volatile("global_load_dword %0, %1, off sc0 sc1" : "+v"(fpreA) : "v"(sflag) : "memory");
        asm volatile("global_load_dword %0, %1, off sc0 sc1" : "+v"(fpreB) : "v"(sflag) : "memory");
    }
    xq += 3 * (size_t)xstep;          // -> x(3), target of step 0's prefetch
    __syncthreads();

#pragma unroll 1
    for (int t = 0; t < LMAXc; t += 2) {
        STEP(t,     0, rA, fpreA)
        STEP(t + 1, 1, rB, fpreB)
    }

    // epilogue: drain everything, publish final flag = LMAX
    drain_vmem();
    if (lane == 0) {
        int fin = LMAXc;
        asm volatile("global_store_dword %0, %1, off sc0 sc1"
                     :: "v"(myflag), "v"(fin) : "memory");
    }
    c2[(size_t)l * 4096 + (g * 4 + quad) * 128 + cell] = 0.25f * cst;
}

// ---------------- head: BN3 + MLP + relu(sum), single WG fp32
DEVI void bn_rows_dev(float* X, int K, const float* g, const float* bb,
                      float* mv, int tid)
{
    __syncthreads();
    if (tid < 32) {
        float s = 0.f, ss = 0.f;
        const float* r = X + tid * K;
        for (int k = 0; k < K; ++k) { float v = r[k]; s += v; ss += v * v; }
        float m = s / (float)K;
        float vv = ss / (float)K - m * m;
        mv[tid]      = m;
        mv[32 + tid] = rsqrtf(fmaxf(vv, 0.f) + EPSc);
    }
    __syncthreads();
    for (int i = tid; i < 32 * K; i += 256) {
        int b = i / K;
        X[i] = (X[i] - mv[b]) * mv[32 + b] * g[b] + bb[b];
    }
    __syncthreads();
}

DEVI void lin_dev(const float* X, int K, const float* W, const float* bias,
                  int NO, float* Y, int relu, int tid)
{
    __syncthreads();
    for (int i = tid; i < 32 * NO; i += 256) {
        int b = i / NO, j = i - b * NO;
        float a = bias[j];
        const float* xr = X + b * K;
        const float* wr = W + j * K;
        for (int k = 0; k < K; ++k) a += xr[k] * wr[k];
        Y[i] = relu ? fmaxf(a, 0.f) : a;
    }
    __syncthreads();
}

__global__ void __launch_bounds__(256)
k_head(const float* __restrict__ c2, const float* __restrict__ g3, const float* __restrict__ bb3,
       const float* w1, const float* b1, const float* w2, const float* b2,
       const float* w22, const float* b22, const float* w3, const float* b3,
       const float* w4, const float* b4, const float* w5, const float* b5,
       float* __restrict__ out)
{
    __shared__ float A[32 * 128];
    __shared__ float Bf[32 * 128];
    __shared__ float mv[64];
    const int tid = threadIdx.x;

    for (int i = tid; i < 32 * 128; i += 256)
        A[i] = c2[i] + c2[4096 + i] + c2[8192 + i] + c2[12288 + i];
    bn_rows_dev(A, 128, g3, bb3, mv, tid);
    lin_dev(A, 128, w1, b1, 128, Bf, 1, tid);
    lin_dev(Bf, 128, w2, b2, 64, A, 1, tid);
    bn_rows_dev(A, 64, g3, bb3, mv, tid);
    lin_dev(A, 64, w22, b22, 64, Bf, 1, tid);
    lin_dev(Bf, 64, w3, b3, 32, A, 1, tid);
    lin_dev(A, 32, w4, b4, 32, Bf, 1, tid);
    lin_dev(Bf, 32, w5, b5, 16, A, 0, tid);
    if (tid < 32) {
        float s = 0.f;
        for (int j = 0; j < 16; ++j) s += A[tid * 16 + j];
        out[tid] = fmaxf(s, 0.f);
    }
}

// ---------------- host
extern "C" void kernel_launch(void* const* d_in, const int* in_sizes, int n_in,
                              void* d_out, int out_size, void* d_ws, size_t ws_size,
                              hipStream_t stream)
{
    const int*   atoms  = (const int*)d_in[0];
    const int*   lens   = (const int*)d_in[2];
    const float* embw   = (const float*)d_in[5];
    const float* l1Wih0 = (const float*)d_in[6];
    const float* l1Whh0 = (const float*)d_in[7];
    const float* l1b0   = (const float*)d_in[8];
    const float* l1Wih  = (const float*)d_in[9];
    const float* l1Whh  = (const float*)d_in[10];
    const float* l1b    = (const float*)d_in[11];
    const float* l2Wih0 = (const float*)d_in[12];
    const float* l2Whh0 = (const float*)d_in[13];
    const float* l2b0   = (const float*)d_in[14];
    const float* l2Wih  = (const float*)d_in[15];
    const float* l2Whh  = (const float*)d_in[16];
    const float* l2b    = (const float*)d_in[17];
    const float* bn2g   = (const float*)d_in[18];
    const float* bn2b   = (const float*)d_in[19];
    const float* bn3g   = (const float*)d_in[20];
    const float* bn3b   = (const float*)d_in[21];
    const float* w1  = (const float*)d_in[22]; const float* b1  = (const float*)d_in[23];
    const float* w2  = (const float*)d_in[24]; const float* b2  = (const float*)d_in[25];
    const float* w22 = (const float*)d_in[26]; const float* b22 = (const float*)d_in[27];
    const float* w3  = (const float*)d_in[28]; const float* b3  = (const float*)d_in[29];
    const float* w4  = (const float*)d_in[30]; const float* b4  = (const float*)d_in[31];
    const float* w5  = (const float*)d_in[32]; const float* b5  = (const float*)d_in[33];
    float* out = (float*)d_out;

    char* base = (char*)d_ws;
    size_t off = 0;
    auto take = [&](size_t bytes) -> char* {
        char* p = base + off;
        off = (off + bytes + 255) & ~(size_t)255;
        return p;
    };
    _Float16* seq1f  = (_Float16*)take((size_t)NTc * H1c * 2);               // 63.6 MB
    float*    dacc   = (float*)take((size_t)Ntot * H1c * 4);                 // 6.4 MB
    _Float16* wcomb1 = (_Float16*)take((size_t)4 * 256 * 128 * 2);           // 256 KB
    _Float16* wih16  = (_Float16*)take((size_t)4 * 512 * 128 * 2);           // 512 KB
    _Float16* whh16  = (_Float16*)take((size_t)4 * 512 * 128 * 2);           // 512 KB
    _Float16* seqA   = (_Float16*)take((size_t)R2c * 128 * 2);               // 8.4 MB
    _Float16* hbuf   = (_Float16*)take((size_t)4 * 8 * LMAXc * 512 * 2);     // 32 MB
    int*      flags  = (int*)take(512 * sizeof(int));
    float*    stats  = (float*)take(1024);
    float*    c2     = (float*)take((size_t)4 * 32 * 128 * 4);

    // weight preps (prepw2 also resets flags for this launch)
    k_prepw1<<<(4 * 256 * 128 + 255) / 256, 256, 0, stream>>>(l1Wih0, l1Whh0, l1Wih, l1Whh, wcomb1);
    k_prepw2<<<(2 * 4 * 512 * 128 + 255) / 256, 256, 0, stream>>>(l2Wih0, l2Wih, l2Whh0, l2Whh, wih16, whh16, flags);

    // LSTM1: embed + 4 layers fused
    k_scan1all<<<Ntot / 32, 256, 0, stream>>>(atoms, embw, wcomb1, l1b0, l1b, seq1f, dacc);

    k_bn2_stats<<<32, 256, 0, stream>>>(lens, dacc, stats);
    k_bn2_apply<<<(R2c * 128 + 255) / 256, 256, 0, stream>>>(dacc, stats, lens, bn2g, bn2b, seqA);

    // LSTM2: all 4 layers wavefront-pipelined in one kernel
    k_scan2p<<<32, 512, 0, stream>>>(seqA, wih16, whh16, l2b0, l2b, hbuf, flags, c2);

    k_head<<<1, 256, 0, stream>>>(c2, bn3g, bn3b, w1, b1, w2, b2, w22, b22,
                                  w3, b3, w4, b4, w5, b5, out);

    (void)in_sizes; (void)n_in; (void)out_size; (void)ws_size;
}